// Round 12
// baseline (191.308 us; speedup 1.0000x reference)
//
#include <hip/hip_runtime.h>

#define EPSF 1e-12f
#define FLTMAX 3.402823466e+38f

constexpr int B = 8, V = 6890, F = 13776, N = 4096;
constexpr int BF = B * F;
constexpr int BN = B * N;
constexpr int CHUNK = 512;
constexpr int NCHUNK = (F + CHUNK - 1) / CHUNK;   // 27
constexpr int SCAN_BLOCKS = B * NCHUNK;           // 216

__device__ __forceinline__ float block_sum_256(float v, float* s4) {
  #pragma unroll
  for (int off = 32; off > 0; off >>= 1) v += __shfl_down(v, off, 64);
  __syncthreads();
  if ((threadIdx.x & 63) == 0) s4[threadIdx.x >> 6] = v;
  __syncthreads();
  return s4[0] + s4[1] + s4[2] + s4[3];
}

__device__ __forceinline__ float face_geom(const float* __restrict__ pv,
                                           const int* __restrict__ pf,
                                           int b, int f, float4* __restrict__ nrm4,
                                           float& es) {
  if (f >= F) return 0.f;
  int i0 = pf[f * 3 + 0], i1 = pf[f * 3 + 1], i2 = pf[f * 3 + 2];
  const float* vb = pv + (size_t)b * V * 3;
  float x0 = vb[i0 * 3 + 0], y0 = vb[i0 * 3 + 1], z0 = vb[i0 * 3 + 2];
  float x1 = vb[i1 * 3 + 0], y1 = vb[i1 * 3 + 1], z1 = vb[i1 * 3 + 2];
  float x2 = vb[i2 * 3 + 0], y2 = vb[i2 * 3 + 1], z2 = vb[i2 * 3 + 2];
  float ax = x1 - x0, ay = y1 - y0, az = z1 - z0;
  float bx = x2 - x0, by = y2 - y0, bz = z2 - z0;
  float cx = ay * bz - az * by;
  float cy = az * bx - ax * bz;
  float cz = ax * by - ay * bx;
  float cn = sqrtf(cx * cx + cy * cy + cz * cz);
  float inv = 1.f / (cn + EPSF);
  nrm4[(size_t)b * F + f] = make_float4(cx * inv, cy * inv, cz * inv, 0.f);
  float ex = x0 - x1, ey = y0 - y1, ez = z0 - z1;
  es += ex * ex + ey * ey + ez * ez;
  ex = x1 - x2; ey = y1 - y2; ez = z1 - z2;
  es += ex * ex + ey * ey + ez * ez;
  es += bx * bx + by * by + bz * bz;
  return 0.5f * cn;
}

// K1: face geometry + per-chunk scan + all init (best arrays, counters, acc).
__global__ __launch_bounds__(256) void scan_faces_kernel(
    const float* __restrict__ pv, const int* __restrict__ pf,
    float* __restrict__ cdf, float* __restrict__ csum, float4* __restrict__ nrm4,
    float* __restrict__ edgep,
    unsigned* __restrict__ best1, unsigned* __restrict__ best2,
    float* __restrict__ acc, unsigned* __restrict__ cnt) {
  __shared__ float wsum[4];
  __shared__ float s4[4];
  int b = blockIdx.x / NCHUNK, ck = blockIdx.x % NCHUNK;
  int lane = threadIdx.x & 63, wid = threadIdx.x >> 6;

  int gid = blockIdx.x * 256 + threadIdx.x;
  if (gid < BN) { best1[gid] = 0xFFFFFFFFu; best2[gid] = 0xFFFFFFFFu; }
  if (gid < 2) acc[gid] = 0.f;
  if (gid == 2) *cnt = 0u;

  int f0 = ck * CHUNK + 2 * threadIdx.x;
  float es = 0.f;
  float a0 = face_geom(pv, pf, b, f0, nrm4, es);
  float a1 = face_geom(pv, pf, b, f0 + 1, nrm4, es);
  float ts = a0 + a1;
  float x = ts;
  #pragma unroll
  for (int off = 1; off < 64; off <<= 1) {
    float y = __shfl_up(x, off, 64);
    if (lane >= off) x += y;
  }
  if (lane == 63) wsum[wid] = x;
  __syncthreads();
  float woff = 0.f;
  for (int w = 0; w < wid; ++w) woff += wsum[w];
  float excl = woff + x - ts;
  size_t g0 = (size_t)b * F + f0;
  if (f0 < F) cdf[g0] = excl + a0;
  if (f0 + 1 < F) cdf[g0 + 1] = excl + ts;
  if (threadIdx.x == 255) csum[blockIdx.x] = woff + x;   // raw chunk total

  float te = block_sum_256(es, s4);
  if (threadIdx.x == 0) edgep[blockIdx.x] = te;
}

// K2: sample 2*B*N points (on-the-fly chunk-total scan + in-chunk binary search).
__global__ __launch_bounds__(256) void sample_kernel(
    const float* __restrict__ pv, const int* __restrict__ pf,
    const float* __restrict__ cdf, const float* __restrict__ csum,
    const float4* __restrict__ nrm4,
    const float* __restrict__ rp, const float* __restrict__ rg,
    float4* __restrict__ pc4, float4* __restrict__ pn4,
    float4* __restrict__ gc4, float4* __restrict__ gn4) {
  int idx = blockIdx.x * 256 + threadIdx.x;
  if (idx >= 2 * BN) return;
  int set = (idx >= BN) ? 1 : 0;
  int i = idx - set * BN;
  int b = i / N;
  const float* r = (set ? rg : rp) + (size_t)i * 3;
  float u = r[0], r1 = r[1], r2 = r[2];

  const float* cs = csum + b * NCHUNK;
  float total = 0.f;
  #pragma unroll
  for (int k2 = 0; k2 < NCHUNK; ++k2) total += cs[k2];
  float target = u * (total + EPSF);

  int k = 0;
  float s = cs[0];
  while (s < target && k < NCHUNK - 1) { ++k; s += cs[k]; }
  float prefix = s - cs[k];
  float t2 = target - prefix;

  const float* c = cdf + (size_t)b * F + k * CHUNK;
  int base = k * CHUNK;
  int lo = 0, hi = CHUNK;
  while (lo < hi) {
    int mid = (lo + hi) >> 1;
    float v = (base + mid < F) ? c[mid] : FLTMAX;
    if (v < t2) lo = mid + 1; else hi = mid;
  }
  int f = base + lo;
  if (f > F - 1) f = F - 1;

  int i0 = pf[f * 3 + 0], i1 = pf[f * 3 + 1], i2 = pf[f * 3 + 2];
  const float* vb = pv + (size_t)b * V * 3;
  float su = sqrtf(r1);
  float w0 = 1.f - su, w1 = su * (1.f - r2), w2 = su * r2;
  float px = w0 * vb[i0 * 3 + 0] + w1 * vb[i1 * 3 + 0] + w2 * vb[i2 * 3 + 0];
  float py = w0 * vb[i0 * 3 + 1] + w1 * vb[i1 * 3 + 1] + w2 * vb[i2 * 3 + 1];
  float pz = w0 * vb[i0 * 3 + 2] + w1 * vb[i1 * 3 + 2] + w2 * vb[i2 * 3 + 2];
  float4* pts = (set ? gc4 : pc4);
  float4* pns = (set ? gn4 : pn4);
  pts[i] = make_float4(px, py, pz, px * px + py * py + pz * pz);
  pns[i] = nrm4[(size_t)b * F + f];
}

// K3: shared-d tiled chamfer, 128 rows x 256 cols per block (two 128-col chunks).
// Each d computed once; row argmin via packed key (trunc-d | col), col min via
// raw bits. prow/q setup amortized over 2 chunks; best1 atomics halved vs R11.
// Grid 4096 = 8b x 32tn x 16tm2. launch_bounds(256,6): VGPR budget 85 (R10:
// budget 64 spilled -> 30x HBM traffic; do not lower).
__global__ __launch_bounds__(256, 6) void chamfer_kernel(
    const float4* __restrict__ pc4, const float4* __restrict__ gc4,
    unsigned* __restrict__ best1, unsigned* __restrict__ best2) {
  const int tid = threadIdx.x;
  const int b = blockIdx.x >> 9;           // 512 blocks/batch
  const int tn = (blockIdx.x >> 4) & 31;   // row tile (pc), 128 rows
  const int tm2 = blockIdx.x & 15;         // col super-tile (gc), 256 cols
  const int ty = tid >> 4, tx = tid & 15;
  const int r0 = tn * 128 + ty * 8;
  const float4* __restrict__ prow = pc4 + (size_t)b * N + r0;

  float qx[8], qy[8], qz[8], pp[8];
  #pragma unroll
  for (int i = 0; i < 8; ++i) {
    float4 p = prow[i];
    qx[i] = -2.f * p.x; qy[i] = -2.f * p.y; qz[i] = -2.f * p.z; pp[i] = p.w;
  }

  unsigned rkey[8];
  #pragma unroll
  for (int i = 0; i < 8; ++i) rkey[i] = 0xFFFFFFFFu;

  __shared__ unsigned mrg[2176];   // 128*17 (rows) == 16*136 (cols), reused

  #pragma unroll
  for (int ch = 0; ch < 2; ++ch) {
    const int cb = (tm2 * 2 + ch) * 128;   // chunk col base
    const int c0 = cb + tx;                // this thread's cols: c0 + 16j
    const float4* __restrict__ gcol = gc4 + (size_t)b * N + c0;
    float4 G[8];
    #pragma unroll
    for (int j = 0; j < 8; ++j) G[j] = gcol[16 * j];   // coalesced

    unsigned cbit[8];
    #pragma unroll
    for (int j = 0; j < 8; ++j) cbit[j] = 0xFFFFFFFFu;

    #pragma unroll
    for (int i = 0; i < 8; ++i) {
      #pragma unroll
      for (int j = 0; j < 8; ++j) {
        // d = |p|^2 + |g|^2 - 2 p.g (same form as reference)
        float dp = fmaf(qx[i], G[j].x, fmaf(qy[i], G[j].y, fmaf(qz[i], G[j].z, G[j].w)));
        float d  = dp + pp[i];
        unsigned db = __float_as_uint(d);
        rkey[i] = min(rkey[i], (db & 0xFFFFF000u) | (unsigned)(c0 + 16 * j));
        cbit[j] = min(cbit[j], db);
      }
    }

    // ---- col merge (banks (8ty+16j+tx)%32 -> 2-way max, free) ----
    if (ch) __syncthreads();               // protect mrg reuse from chunk 0 reads
    #pragma unroll
    for (int j = 0; j < 8; ++j) mrg[ty * 136 + 16 * j + tx] = cbit[j];
    __syncthreads();
    if (tid < 128) {
      unsigned best = 0xFFFFFFFFu;
      #pragma unroll
      for (int k = 0; k < 16; ++k) best = min(best, mrg[k * 136 + tid]);
      atomicMin(&best2[(size_t)b * N + cb + tid], best);
    }
    __syncthreads();                       // mrg free for next phase
  }

  // ---- row merge (stride 17: 2-way max, free) ----
  #pragma unroll
  for (int i = 0; i < 8; ++i) mrg[(ty * 8 + i) * 17 + tx] = rkey[i];
  __syncthreads();
  if (tid < 128) {
    unsigned best = 0xFFFFFFFFu;
    #pragma unroll
    for (int k = 0; k < 16; ++k) best = min(best, mrg[tid * 17 + k]);
    atomicMin(&best1[(size_t)b * N + tn * 128 + tid], best);
  }
}

// K4: finalize — row sums + normal loss; ticketed last block folds edge + writes out.
__global__ __launch_bounds__(256) void finalize_kernel(
    const unsigned* __restrict__ best1, const unsigned* __restrict__ best2,
    const float4* __restrict__ pn4, const float4* __restrict__ gn4,
    const float* __restrict__ edgep,
    float* __restrict__ acc, unsigned* __restrict__ cnt, float* __restrict__ out) {
  __shared__ float s4[4];
  __shared__ unsigned tk;
  int i = blockIdx.x * 256 + threadIdx.x;
  int b = i >> 12;
  unsigned k1 = best1[i];
  float d1 = __uint_as_float(k1 & 0xFFFFF000u);   // truncated min distance
  int m = (int)(k1 & 0xFFFu);                     // 12-bit col index (N=4096)
  float d2 = __uint_as_float(best2[i]);
  float4 a = pn4[i];
  float4 g = gn4[((size_t)b << 12) + m];
  float nl = 1.f - fabsf(a.x * g.x + a.y * g.y + a.z * g.z);
  float sd = block_sum_256(d1 + d2, s4);
  float sn = block_sum_256(nl, s4);
  if (threadIdx.x == 0) {
    atomicAdd(&acc[0], sd);
    atomicAdd(&acc[1], sn);
    __asm__ __volatile__("s_waitcnt vmcnt(0)" ::: "memory");
    tk = atomicAdd(cnt, 1u);
  }
  __syncthreads();
  if (tk == 127) {                     // last of 128 blocks
    float e = (threadIdx.x < SCAN_BLOCKS) ? edgep[threadIdx.x] : 0.f;
    float te = block_sum_256(e, s4);
    if (threadIdx.x == 0) {
      float chamf = atomicAdd(&acc[0], 0.f);
      float nsum  = atomicAdd(&acc[1], 0.f);
      float inv_bn = 1.f / (float)BN;
      out[0] = chamf * inv_bn + 0.1f * (nsum * inv_bn) + 0.5f * (te / (3.f * (float)BF));
    }
  }
}

extern "C" void kernel_launch(void* const* d_in, const int* in_sizes, int n_in,
                              void* d_out, int out_size, void* d_ws, size_t ws_size,
                              hipStream_t stream) {
  const float* pv = (const float*)d_in[0];   // predicted_vertices [B,V,3]
  const int*   pf = (const int*)d_in[1];     // predicted_faces [F,3]
  // d_in[2]/d_in[3] (gt mesh) are unused by the reference.
  const float* rp = (const float*)d_in[4];   // rand_pred [B,N,3]
  const float* rg = (const float*)d_in[5];   // rand_gt   [B,N,3]
  float* out = (float*)d_out;

  unsigned* best1 = (unsigned*)d_ws;                       // BN u32
  unsigned* best2 = best1 + BN;                            // BN u32
  float4* pc4  = (float4*)(best2 + BN);                    // BN
  float4* pn4  = pc4 + BN;                                 // BN
  float4* gc4  = pn4 + BN;                                 // BN
  float4* gn4  = gc4 + BN;                                 // BN
  float4* nrm4 = gn4 + BN;                                 // BF
  float* cdf   = (float*)(nrm4 + BF);                      // BF
  float* csum  = cdf + BF;                                 // 216
  float* edgep = csum + SCAN_BLOCKS;                       // 216
  float* acc   = edgep + SCAN_BLOCKS;                      // 2
  unsigned* cnt = (unsigned*)(acc + 2);                    // 1

  scan_faces_kernel<<<SCAN_BLOCKS, 256, 0, stream>>>(pv, pf, cdf, csum, nrm4, edgep,
                                                     best1, best2, acc, cnt);
  sample_kernel<<<(2 * BN) / 256, 256, 0, stream>>>(pv, pf, cdf, csum, nrm4,
                                                    rp, rg, pc4, pn4, gc4, gn4);
  chamfer_kernel<<<8 * 32 * 16, 256, 0, stream>>>(pc4, gc4, best1, best2);
  finalize_kernel<<<BN / 256, 256, 0, stream>>>(best1, best2, pn4, gn4, edgep,
                                                acc, cnt, out);
}

// Round 13
// 105.949 us; speedup vs baseline: 1.8057x; 1.8057x over previous
//
#include <hip/hip_runtime.h>

#define EPSF 1e-12f
#define FLTMAX 3.402823466e+38f

constexpr int B = 8, V = 6890, F = 13776, N = 4096;
constexpr int BF = B * F;
constexpr int BN = B * N;
constexpr int CHUNK = 512;
constexpr int NCHUNK = (F + CHUNK - 1) / CHUNK;   // 27
constexpr int SCAN_BLOCKS = B * NCHUNK;           // 216

__device__ __forceinline__ float block_sum_256(float v, float* s4) {
  #pragma unroll
  for (int off = 32; off > 0; off >>= 1) v += __shfl_down(v, off, 64);
  __syncthreads();
  if ((threadIdx.x & 63) == 0) s4[threadIdx.x >> 6] = v;
  __syncthreads();
  return s4[0] + s4[1] + s4[2] + s4[3];
}

__device__ __forceinline__ float face_geom(const float* __restrict__ pv,
                                           const int* __restrict__ pf,
                                           int b, int f, float4* __restrict__ nrm4,
                                           float& es) {
  if (f >= F) return 0.f;
  int i0 = pf[f * 3 + 0], i1 = pf[f * 3 + 1], i2 = pf[f * 3 + 2];
  const float* vb = pv + (size_t)b * V * 3;
  float x0 = vb[i0 * 3 + 0], y0 = vb[i0 * 3 + 1], z0 = vb[i0 * 3 + 2];
  float x1 = vb[i1 * 3 + 0], y1 = vb[i1 * 3 + 1], z1 = vb[i1 * 3 + 2];
  float x2 = vb[i2 * 3 + 0], y2 = vb[i2 * 3 + 1], z2 = vb[i2 * 3 + 2];
  float ax = x1 - x0, ay = y1 - y0, az = z1 - z0;
  float bx = x2 - x0, by = y2 - y0, bz = z2 - z0;
  float cx = ay * bz - az * by;
  float cy = az * bx - ax * bz;
  float cz = ax * by - ay * bx;
  float cn = sqrtf(cx * cx + cy * cy + cz * cz);
  float inv = 1.f / (cn + EPSF);
  nrm4[(size_t)b * F + f] = make_float4(cx * inv, cy * inv, cz * inv, 0.f);
  float ex = x0 - x1, ey = y0 - y1, ez = z0 - z1;
  es += ex * ex + ey * ey + ez * ez;
  ex = x1 - x2; ey = y1 - y2; ez = z1 - z2;
  es += ex * ex + ey * ey + ez * ez;
  es += bx * bx + by * by + bz * bz;
  return 0.5f * cn;
}

// K1: face geometry + per-chunk scan + all init (best arrays, counters, acc).
__global__ __launch_bounds__(256) void scan_faces_kernel(
    const float* __restrict__ pv, const int* __restrict__ pf,
    float* __restrict__ cdf, float* __restrict__ csum, float4* __restrict__ nrm4,
    float* __restrict__ edgep,
    unsigned* __restrict__ best1, unsigned* __restrict__ best2,
    float* __restrict__ acc, unsigned* __restrict__ cnt) {
  __shared__ float wsum[4];
  __shared__ float s4[4];
  int b = blockIdx.x / NCHUNK, ck = blockIdx.x % NCHUNK;
  int lane = threadIdx.x & 63, wid = threadIdx.x >> 6;

  int gid = blockIdx.x * 256 + threadIdx.x;
  if (gid < BN) { best1[gid] = 0xFFFFFFFFu; best2[gid] = 0xFFFFFFFFu; }
  if (gid < 2) acc[gid] = 0.f;
  if (gid == 2) *cnt = 0u;

  int f0 = ck * CHUNK + 2 * threadIdx.x;
  float es = 0.f;
  float a0 = face_geom(pv, pf, b, f0, nrm4, es);
  float a1 = face_geom(pv, pf, b, f0 + 1, nrm4, es);
  float ts = a0 + a1;
  float x = ts;
  #pragma unroll
  for (int off = 1; off < 64; off <<= 1) {
    float y = __shfl_up(x, off, 64);
    if (lane >= off) x += y;
  }
  if (lane == 63) wsum[wid] = x;
  __syncthreads();
  float woff = 0.f;
  for (int w = 0; w < wid; ++w) woff += wsum[w];
  float excl = woff + x - ts;
  size_t g0 = (size_t)b * F + f0;
  if (f0 < F) cdf[g0] = excl + a0;
  if (f0 + 1 < F) cdf[g0 + 1] = excl + ts;
  if (threadIdx.x == 255) csum[blockIdx.x] = woff + x;   // raw chunk total

  float te = block_sum_256(es, s4);
  if (threadIdx.x == 0) edgep[blockIdx.x] = te;
}

// K2: sample 2*B*N points (on-the-fly chunk-total scan + in-chunk binary search).
__global__ __launch_bounds__(256) void sample_kernel(
    const float* __restrict__ pv, const int* __restrict__ pf,
    const float* __restrict__ cdf, const float* __restrict__ csum,
    const float4* __restrict__ nrm4,
    const float* __restrict__ rp, const float* __restrict__ rg,
    float4* __restrict__ pc4, float4* __restrict__ pn4,
    float4* __restrict__ gc4, float4* __restrict__ gn4) {
  int idx = blockIdx.x * 256 + threadIdx.x;
  if (idx >= 2 * BN) return;
  int set = (idx >= BN) ? 1 : 0;
  int i = idx - set * BN;
  int b = i / N;
  const float* r = (set ? rg : rp) + (size_t)i * 3;
  float u = r[0], r1 = r[1], r2 = r[2];

  const float* cs = csum + b * NCHUNK;
  float total = 0.f;
  #pragma unroll
  for (int k2 = 0; k2 < NCHUNK; ++k2) total += cs[k2];
  float target = u * (total + EPSF);

  int k = 0;
  float s = cs[0];
  while (s < target && k < NCHUNK - 1) { ++k; s += cs[k]; }
  float prefix = s - cs[k];
  float t2 = target - prefix;

  const float* c = cdf + (size_t)b * F + k * CHUNK;
  int base = k * CHUNK;
  int lo = 0, hi = CHUNK;
  while (lo < hi) {
    int mid = (lo + hi) >> 1;
    float v = (base + mid < F) ? c[mid] : FLTMAX;
    if (v < t2) lo = mid + 1; else hi = mid;
  }
  int f = base + lo;
  if (f > F - 1) f = F - 1;

  int i0 = pf[f * 3 + 0], i1 = pf[f * 3 + 1], i2 = pf[f * 3 + 2];
  const float* vb = pv + (size_t)b * V * 3;
  float su = sqrtf(r1);
  float w0 = 1.f - su, w1 = su * (1.f - r2), w2 = su * r2;
  float px = w0 * vb[i0 * 3 + 0] + w1 * vb[i1 * 3 + 0] + w2 * vb[i2 * 3 + 0];
  float py = w0 * vb[i0 * 3 + 1] + w1 * vb[i1 * 3 + 1] + w2 * vb[i2 * 3 + 1];
  float pz = w0 * vb[i0 * 3 + 2] + w1 * vb[i1 * 3 + 2] + w2 * vb[i2 * 3 + 2];
  float4* pts = (set ? gc4 : pc4);
  float4* pns = (set ? gn4 : pn4);
  pts[i] = make_float4(px, py, pz, px * px + py * py + pz * pz);
  pns[i] = nrm4[(size_t)b * F + f];
}

// K3: shared-d tiled chamfer (R11 config — session best; DO NOT add live state
// across the merge barriers: R10 (budget 64) and R12 (2-chunk rkey) both spilled
// to scratch, 5x regression). Each d computed ONCE; row argmin via packed key
// (trunc-d | col), col min via raw bits. Block 16x16 threads, 8x8 subtile,
// col mapping c0 + 16j (coalesced loads, 2-way-max LDS merges).
// Grid 8192 = 8b x 32 x 32. launch_bounds(256,6): VGPR budget 85, uses 44.
__global__ __launch_bounds__(256, 6) void chamfer_kernel(
    const float4* __restrict__ pc4, const float4* __restrict__ gc4,
    unsigned* __restrict__ best1, unsigned* __restrict__ best2) {
  const int tid = threadIdx.x;
  const int b = blockIdx.x >> 10;          // 1024 tiles/batch
  const int tn = (blockIdx.x >> 5) & 31;   // row tile (pc)
  const int tm = blockIdx.x & 31;          // col tile (gc)
  const int ty = tid >> 4, tx = tid & 15;
  const int r0 = tn * 128 + ty * 8;        // rows: r0..r0+7 (consecutive)
  const int c0 = tm * 128 + tx;            // cols: c0 + 16j (strided)
  const float4* __restrict__ prow = pc4 + (size_t)b * N + r0;
  const float4* __restrict__ gcol = gc4 + (size_t)b * N + c0;

  float qx[8], qy[8], qz[8], pp[8];
  float4 G[8];
  #pragma unroll
  for (int i = 0; i < 8; ++i) {
    float4 p = prow[i];
    qx[i] = -2.f * p.x; qy[i] = -2.f * p.y; qz[i] = -2.f * p.z; pp[i] = p.w;
  }
  #pragma unroll
  for (int j = 0; j < 8; ++j) G[j] = gcol[16 * j];   // 16 lanes -> 16 consecutive float4

  unsigned rkey[8], cbit[8];
  #pragma unroll
  for (int i = 0; i < 8; ++i) { rkey[i] = 0xFFFFFFFFu; cbit[i] = 0xFFFFFFFFu; }

  #pragma unroll
  for (int i = 0; i < 8; ++i) {
    #pragma unroll
    for (int j = 0; j < 8; ++j) {
      // d = |p|^2 + |g|^2 - 2 p.g (same form as reference)
      float dp = fmaf(qx[i], G[j].x, fmaf(qy[i], G[j].y, fmaf(qz[i], G[j].z, G[j].w)));
      float d  = dp + pp[i];
      unsigned db = __float_as_uint(d);
      rkey[i] = min(rkey[i], (db & 0xFFFFF000u) | (unsigned)(c0 + 16 * j));
      cbit[j] = min(cbit[j], db);
    }
  }

  __shared__ unsigned mrg[2176];   // 128*17 (rows) == 16*136 (cols), reused
  // ---- row merge (stride 17: 2-way max, free) ----
  #pragma unroll
  for (int i = 0; i < 8; ++i) mrg[(ty * 8 + i) * 17 + tx] = rkey[i];
  __syncthreads();
  if (tid < 128) {
    unsigned best = 0xFFFFFFFFu;
    #pragma unroll
    for (int k = 0; k < 16; ++k) best = min(best, mrg[tid * 17 + k]);
    atomicMin(&best1[(size_t)b * N + tn * 128 + tid], best);
  }
  __syncthreads();
  // ---- col merge (stride 136: banks (8ty+16j+tx)%32 -> 2-way max, free) ----
  #pragma unroll
  for (int j = 0; j < 8; ++j) mrg[ty * 136 + 16 * j + tx] = cbit[j];
  __syncthreads();
  if (tid < 128) {
    unsigned best = 0xFFFFFFFFu;
    #pragma unroll
    for (int k = 0; k < 16; ++k) best = min(best, mrg[k * 136 + tid]);
    atomicMin(&best2[(size_t)b * N + tm * 128 + tid], best);
  }
}

// K4: finalize — row sums + normal loss; ticketed last block folds edge + writes out.
__global__ __launch_bounds__(256) void finalize_kernel(
    const unsigned* __restrict__ best1, const unsigned* __restrict__ best2,
    const float4* __restrict__ pn4, const float4* __restrict__ gn4,
    const float* __restrict__ edgep,
    float* __restrict__ acc, unsigned* __restrict__ cnt, float* __restrict__ out) {
  __shared__ float s4[4];
  __shared__ unsigned tk;
  int i = blockIdx.x * 256 + threadIdx.x;
  int b = i >> 12;
  unsigned k1 = best1[i];
  float d1 = __uint_as_float(k1 & 0xFFFFF000u);   // truncated min distance
  int m = (int)(k1 & 0xFFFu);                     // 12-bit col index (N=4096)
  float d2 = __uint_as_float(best2[i]);
  float4 a = pn4[i];
  float4 g = gn4[((size_t)b << 12) + m];
  float nl = 1.f - fabsf(a.x * g.x + a.y * g.y + a.z * g.z);
  float sd = block_sum_256(d1 + d2, s4);
  float sn = block_sum_256(nl, s4);
  if (threadIdx.x == 0) {
    atomicAdd(&acc[0], sd);
    atomicAdd(&acc[1], sn);
    __asm__ __volatile__("s_waitcnt vmcnt(0)" ::: "memory");
    tk = atomicAdd(cnt, 1u);
  }
  __syncthreads();
  if (tk == 127) {                     // last of 128 blocks
    float e = (threadIdx.x < SCAN_BLOCKS) ? edgep[threadIdx.x] : 0.f;
    float te = block_sum_256(e, s4);
    if (threadIdx.x == 0) {
      float chamf = atomicAdd(&acc[0], 0.f);
      float nsum  = atomicAdd(&acc[1], 0.f);
      float inv_bn = 1.f / (float)BN;
      out[0] = chamf * inv_bn + 0.1f * (nsum * inv_bn) + 0.5f * (te / (3.f * (float)BF));
    }
  }
}

extern "C" void kernel_launch(void* const* d_in, const int* in_sizes, int n_in,
                              void* d_out, int out_size, void* d_ws, size_t ws_size,
                              hipStream_t stream) {
  const float* pv = (const float*)d_in[0];   // predicted_vertices [B,V,3]
  const int*   pf = (const int*)d_in[1];     // predicted_faces [F,3]
  // d_in[2]/d_in[3] (gt mesh) are unused by the reference.
  const float* rp = (const float*)d_in[4];   // rand_pred [B,N,3]
  const float* rg = (const float*)d_in[5];   // rand_gt   [B,N,3]
  float* out = (float*)d_out;

  unsigned* best1 = (unsigned*)d_ws;                       // BN u32
  unsigned* best2 = best1 + BN;                            // BN u32
  float4* pc4  = (float4*)(best2 + BN);                    // BN
  float4* pn4  = pc4 + BN;                                 // BN
  float4* gc4  = pn4 + BN;                                 // BN
  float4* gn4  = gc4 + BN;                                 // BN
  float4* nrm4 = gn4 + BN;                                 // BF
  float* cdf   = (float*)(nrm4 + BF);                      // BF
  float* csum  = cdf + BF;                                 // 216
  float* edgep = csum + SCAN_BLOCKS;                       // 216
  float* acc   = edgep + SCAN_BLOCKS;                      // 2
  unsigned* cnt = (unsigned*)(acc + 2);                    // 1

  scan_faces_kernel<<<SCAN_BLOCKS, 256, 0, stream>>>(pv, pf, cdf, csum, nrm4, edgep,
                                                     best1, best2, acc, cnt);
  sample_kernel<<<(2 * BN) / 256, 256, 0, stream>>>(pv, pf, cdf, csum, nrm4,
                                                    rp, rg, pc4, pn4, gc4, gn4);
  chamfer_kernel<<<8 * 32 * 32, 256, 0, stream>>>(pc4, gc4, best1, best2);
  finalize_kernel<<<BN / 256, 256, 0, stream>>>(best1, best2, pn4, gn4, edgep,
                                                acc, cnt, out);
}